// Round 6
// baseline (40.848 us; speedup 1.0000x reference)
//
#include <hip/hip_runtime.h>

#define NN   1024          // N = 32*32
#define NT   9
#define NCH  25            // 9 D + 8 L + 8 U
#define BATCH 2

typedef float f32x4 __attribute__((ext_vector_type(4)));

// out[b, c, i, k]  (B, 25, N, N) float32
// A_t: diag = kappa^2+4; E_n=-1+m1[n]/2 (gx<31); W_n=-1-m1[n]/2 (gx>0);
//      N_n=-1+m2[n]/2 (gy<31); S_n=-1-m2[n]/2 (gy>0).  M_t = I + A_t.
// w[n,t] = 1/tau[n,t]^2
// c=0     : A0^T A0 + 1.05 I
// c=1..8  : M_t^T diag(w_t) M_t  (+ w_t[i] on diag when c<=7), t=c
// c=9..16 : L_t[i,k] = -w[k] * M[k,i], t=c-8
// c=17..24: U_t[i,k] = -w[i] * M[i,k], t=c-16
//
// Row i band offsets (sorted): {-64,-33,-32,-31,-2,-1,0,1,2,31,32,33,64}
// -> slots 0..12; slot 13 (byte 52) is a zero pad. Values wave-uniform per (b,i,c).

__global__ __launch_bounds__(256, 8)
void spde_kernel(const float* __restrict__ kappa,
                 const float* __restrict__ m,
                 const float* __restrict__ tau,
                 float* __restrict__ out) {
    __shared__ float tab[NCH][14];

    const int bid = blockIdx.x;            // 0..2047 = (b, i)
    const int b   = bid >> 10;
    const int i   = bid & (NN - 1);
    const int tid = threadIdx.x;
    const int k0  = tid * 4;

    const int gx = i & 31, gy = i >> 5;
    const bool eE = gx < 31, eW = gx > 0, eN = gy < 31, eS = gy > 0;
    const bool eE2 = gx < 30, eW2 = gx > 1, eN2 = gy < 30, eS2 = gy > 1;

    const float kap   = kappa[0];
    const float diagA = kap * kap + 4.0f;
    const float diagM = kap * kap + 5.0f;

    // ---------- phase 1: thread c (< 25) fills tab[c][0..13] ----------
    if (tid < NCH) {
        const int c = tid;
        const float* __restrict__ m1b = m   + (size_t)(b * 2 + 0) * NN * NT;
        const float* __restrict__ m2b = m   + (size_t)(b * 2 + 1) * NN * NT;
        const float* __restrict__ tb  = tau + (size_t)b * NN * NT;

        float V0=0,V1=0,V2=0,V3=0,V4=0,V5=0,V6=0,V7=0,V8=0,V9=0,V10=0,V11=0,V12=0;

        if (c < 9) {                       // D: M^T diag(w) M (+ extras)
            const int   t  = c;
            const float dg = (c == 0) ? diagA : diagM;
            {   // n = i
                const float m1i = m1b[i*NT+t], m2i = m2b[i*NT+t];
                float wn = 1.0f;
                if (c != 0) { const float ta = tb[i*NT+t]; wn = 1.0f/(ta*ta); }
                const float a = dg * wn;
                V6 += a * dg;
                if (eE) V7  += a * (-1.0f + 0.5f*m1i);
                if (eW) V5  += a * (-1.0f - 0.5f*m1i);
                if (eN) V10 += a * (-1.0f + 0.5f*m2i);
                if (eS) V2  += a * (-1.0f - 0.5f*m2i);
            }
            if (eE) {   // n = i+1,  M[n,i] = W_n
                const int n = i + 1;
                const float m1n = m1b[n*NT+t], m2n = m2b[n*NT+t];
                float wn = 1.0f;
                if (c != 0) { const float ta = tb[n*NT+t]; wn = 1.0f/(ta*ta); }
                const float Wn = -1.0f - 0.5f*m1n;
                const float a  = wn * Wn;
                V7 += a * dg;
                V6 += a * Wn;
                if (eE2) V8  += a * (-1.0f + 0.5f*m1n);
                if (eN)  V11 += a * (-1.0f + 0.5f*m2n);
                if (eS)  V3  += a * (-1.0f - 0.5f*m2n);
            }
            if (eW) {   // n = i-1,  M[n,i] = E_n
                const int n = i - 1;
                const float m1n = m1b[n*NT+t], m2n = m2b[n*NT+t];
                float wn = 1.0f;
                if (c != 0) { const float ta = tb[n*NT+t]; wn = 1.0f/(ta*ta); }
                const float En = -1.0f + 0.5f*m1n;
                const float a  = wn * En;
                V5 += a * dg;
                V6 += a * En;
                if (eW2) V4 += a * (-1.0f - 0.5f*m1n);
                if (eN)  V9 += a * (-1.0f + 0.5f*m2n);
                if (eS)  V1 += a * (-1.0f - 0.5f*m2n);
            }
            if (eN) {   // n = i+32, M[n,i] = S_n
                const int n = i + 32;
                const float m1n = m1b[n*NT+t], m2n = m2b[n*NT+t];
                float wn = 1.0f;
                if (c != 0) { const float ta = tb[n*NT+t]; wn = 1.0f/(ta*ta); }
                const float Sn = -1.0f - 0.5f*m2n;
                const float a  = wn * Sn;
                V10 += a * dg;
                V6  += a * Sn;
                if (eE)  V11 += a * (-1.0f + 0.5f*m1n);
                if (eW)  V9  += a * (-1.0f - 0.5f*m1n);
                if (eN2) V12 += a * (-1.0f + 0.5f*m2n);
            }
            if (eS) {   // n = i-32, M[n,i] = N_n
                const int n = i - 32;
                const float m1n = m1b[n*NT+t], m2n = m2b[n*NT+t];
                float wn = 1.0f;
                if (c != 0) { const float ta = tb[n*NT+t]; wn = 1.0f/(ta*ta); }
                const float Nn = -1.0f + 0.5f*m2n;
                const float a  = wn * Nn;
                V2 += a * dg;
                V6 += a * Nn;
                if (eE)  V3 += a * (-1.0f + 0.5f*m1n);
                if (eW)  V1 += a * (-1.0f - 0.5f*m1n);
                if (eS2) V0 += a * (-1.0f - 0.5f*m2n);
            }
            if (c == 0) V6 += 1.05f;
            else if (c <= 7) { const float ta = tb[i*NT+t]; V6 += 1.0f/(ta*ta); }
        } else if (c < 17) {               // L: L[i,k] = -w[k]*M[k,i]
            const int t = c - 8;
            { const float ta = tb[i*NT+t];      V6  = -(1.0f/(ta*ta)) * diagM; }
            if (eE) { const float ta = tb[(i+1)*NT+t];
                      V7  = -(1.0f/(ta*ta)) * (-1.0f - 0.5f*m1b[(i+1)*NT+t]); }
            if (eW) { const float ta = tb[(i-1)*NT+t];
                      V5  = -(1.0f/(ta*ta)) * (-1.0f + 0.5f*m1b[(i-1)*NT+t]); }
            if (eN) { const float ta = tb[(i+32)*NT+t];
                      V10 = -(1.0f/(ta*ta)) * (-1.0f - 0.5f*m2b[(i+32)*NT+t]); }
            if (eS) { const float ta = tb[(i-32)*NT+t];
                      V2  = -(1.0f/(ta*ta)) * (-1.0f + 0.5f*m2b[(i-32)*NT+t]); }
        } else {                            // U: U[i,k] = -w[i]*M[i,k]
            const int t = c - 16;
            const float ta = tb[i*NT+t];
            const float wi = 1.0f/(ta*ta);
            V6 = -wi * diagM;
            if (eE) V7  = -wi * (-1.0f + 0.5f*m1b[i*NT+t]);
            if (eW) V5  = -wi * (-1.0f - 0.5f*m1b[i*NT+t]);
            if (eN) V10 = -wi * (-1.0f + 0.5f*m2b[i*NT+t]);
            if (eS) V2  = -wi * (-1.0f - 0.5f*m2b[i*NT+t]);
        }

        tab[c][0]=V0;  tab[c][1]=V1;  tab[c][2]=V2;  tab[c][3]=V3;
        tab[c][4]=V4;  tab[c][5]=V5;  tab[c][6]=V6;  tab[c][7]=V7;
        tab[c][8]=V8;  tab[c][9]=V9;  tab[c][10]=V10; tab[c][11]=V11;
        tab[c][12]=V12; tab[c][13]=0.0f;
    }

    // ---------- per-thread slot byte offsets (fixed across channels) ----------
    const int d0 = k0 - i;
    int off0, off1, off2, off3;
    {
        auto slotByte = [](int d) -> int {
            int s = 52;                         // pad (zero)
            s = (d==-64)? 0  : s;  s = (d==-33)? 4  : s;
            s = (d==-32)? 8  : s;  s = (d==-31)? 12 : s;
            s = (d== -2)? 16 : s;  s = (d== -1)? 20 : s;
            s = (d==  0)? 24 : s;  s = (d==  1)? 28 : s;
            s = (d==  2)? 32 : s;  s = (d== 31)? 36 : s;
            s = (d== 32)? 40 : s;  s = (d== 33)? 44 : s;
            s = (d== 64)? 48 : s;
            return s;
        };
        off0 = slotByte(d0);     off1 = slotByte(d0 + 1);
        off2 = slotByte(d0 + 2); off3 = slotByte(d0 + 3);
    }

    __syncthreads();

    float* __restrict__ orow = out + ((size_t)(b * NCH) * NN + i) * NN + k0;

    // ---------- phase 2: pure streaming ----------
    if ((off0 & off1 & off2 & off3) == 52) {
        // entire thread (and usually entire wave) is out-of-band: pure zero streamer
        const f32x4 z = (f32x4)(0.0f);
#pragma unroll
        for (int c = 0; c < NCH; ++c)
            *reinterpret_cast<f32x4*>(orow + (size_t)c * NN * NN) = z;
    } else {
        const char* tb0 = (const char*)&tab[0][0];
        const char* a0 = tb0 + off0;
        const char* a1 = tb0 + off1;
        const char* a2 = tb0 + off2;
        const char* a3 = tb0 + off3;
#pragma unroll
        for (int c = 0; c < NCH; ++c) {
            f32x4 v;
            v[0] = *(const float*)(a0 + c * 56);
            v[1] = *(const float*)(a1 + c * 56);
            v[2] = *(const float*)(a2 + c * 56);
            v[3] = *(const float*)(a3 + c * 56);
            *reinterpret_cast<f32x4*>(orow + (size_t)c * NN * NN) = v;
        }
    }
}

extern "C" void kernel_launch(void* const* d_in, const int* in_sizes, int n_in,
                              void* d_out, int out_size, void* d_ws, size_t ws_size,
                              hipStream_t stream) {
    const float* kappa = (const float*)d_in[0];
    const float* m     = (const float*)d_in[1];
    // d_in[2] = H (unused)
    const float* tau   = (const float*)d_in[3];
    float* out = (float*)d_out;

    spde_kernel<<<BATCH * NN, 256, 0, stream>>>(kappa, m, tau, out);
}

// Round 7
// 38.991 us; speedup vs baseline: 1.0476x; 1.0476x over previous
//
#include <hip/hip_runtime.h>

#define NN   1024          // N = 32*32
#define NT   9
#define NCH  25            // 9 D + 8 L + 8 U
#define BATCH 2

typedef float f32x4 __attribute__((ext_vector_type(4)));

// out[b, c, i, k]  (B, 25, N, N) float32
// A_t: diag = kappa^2+4; E_n=-1+m1[n]/2 (gx<31); W_n=-1-m1[n]/2 (gx>0);
//      N_n=-1+m2[n]/2 (gy<31); S_n=-1-m2[n]/2 (gy>0).  M_t = I + A_t.
// w[n,t] = 1/tau[n,t]^2
// c=0     : A0^T A0 + 1.05 I
// c=1..8  : M_t^T diag(w_t) M_t  (+ w_t[i] on diag when c<=7), t=c
// c=9..16 : L_t[i,k] = -w[k] * M[k,i], t=c-8
// c=17..24: U_t[i,k] = -w[i] * M[i,k], t=c-16
//
// Row i band offsets (sorted): {-64,-33,-32,-31,-2,-1,0,1,2,31,32,33,64}
// -> slots 0..12; slot 13 (byte 52) is a zero pad. Values wave-uniform per (b,i,c).

__global__ __launch_bounds__(256, 8)
void spde_kernel(const float* __restrict__ kappa,
                 const float* __restrict__ m,
                 const float* __restrict__ tau,
                 float* __restrict__ out) {
    __shared__ float tab[NCH][14];

    const int bid = blockIdx.x;            // 0..2047 = (b, i)
    const int b   = bid >> 10;
    const int i   = bid & (NN - 1);
    const int tid = threadIdx.x;
    const int k0  = tid * 4;

    const int gx = i & 31, gy = i >> 5;
    const bool eE = gx < 31, eW = gx > 0, eN = gy < 31, eS = gy > 0;
    const bool eE2 = gx < 30, eW2 = gx > 1, eN2 = gy < 30, eS2 = gy > 1;

    const float kap   = kappa[0];
    const float diagA = kap * kap + 4.0f;
    const float diagM = kap * kap + 5.0f;

    // ---------- per-thread slot byte offsets (fixed across channels) ----------
    const int d0 = k0 - i;
    int off0, off1, off2, off3;
    {
        auto slotByte = [](int d) -> int {
            int s = 52;                         // pad (zero)
            s = (d==-64)? 0  : s;  s = (d==-33)? 4  : s;
            s = (d==-32)? 8  : s;  s = (d==-31)? 12 : s;
            s = (d== -2)? 16 : s;  s = (d== -1)? 20 : s;
            s = (d==  0)? 24 : s;  s = (d==  1)? 28 : s;
            s = (d==  2)? 32 : s;  s = (d== 31)? 36 : s;
            s = (d== 32)? 40 : s;  s = (d== 33)? 44 : s;
            s = (d== 64)? 48 : s;
            return s;
        };
        off0 = slotByte(d0);     off1 = slotByte(d0 + 1);
        off2 = slotByte(d0 + 2); off3 = slotByte(d0 + 3);
    }
    // all four == 52 (pad)?  AND==52 implies bits {2,4,5} set in each -> each==52.
    const bool alloob = ((off0 & off1 & off2 & off3) == 52);

    float* __restrict__ orow = out + ((size_t)(b * NCH) * NN + i) * NN + k0;

    // ---------- phase 1: thread c (< 25) fills tab[c][0..13] ----------
    // (waves 1-3 skip this whole region via s_cbranch_execz and start streaming)
    if (tid < NCH) {
        const int c = tid;
        const float* __restrict__ m1b = m   + (size_t)(b * 2 + 0) * NN * NT;
        const float* __restrict__ m2b = m   + (size_t)(b * 2 + 1) * NN * NT;
        const float* __restrict__ tb  = tau + (size_t)b * NN * NT;

        float V0=0,V1=0,V2=0,V3=0,V4=0,V5=0,V6=0,V7=0,V8=0,V9=0,V10=0,V11=0,V12=0;

        if (c < 9) {                       // D: M^T diag(w) M (+ extras)
            const int   t  = c;
            const float dg = (c == 0) ? diagA : diagM;
            {   // n = i
                const float m1i = m1b[i*NT+t], m2i = m2b[i*NT+t];
                float wn = 1.0f;
                if (c != 0) { const float ta = tb[i*NT+t]; wn = 1.0f/(ta*ta); }
                const float a = dg * wn;
                V6 += a * dg;
                if (eE) V7  += a * (-1.0f + 0.5f*m1i);
                if (eW) V5  += a * (-1.0f - 0.5f*m1i);
                if (eN) V10 += a * (-1.0f + 0.5f*m2i);
                if (eS) V2  += a * (-1.0f - 0.5f*m2i);
            }
            if (eE) {   // n = i+1,  M[n,i] = W_n
                const int n = i + 1;
                const float m1n = m1b[n*NT+t], m2n = m2b[n*NT+t];
                float wn = 1.0f;
                if (c != 0) { const float ta = tb[n*NT+t]; wn = 1.0f/(ta*ta); }
                const float Wn = -1.0f - 0.5f*m1n;
                const float a  = wn * Wn;
                V7 += a * dg;
                V6 += a * Wn;
                if (eE2) V8  += a * (-1.0f + 0.5f*m1n);
                if (eN)  V11 += a * (-1.0f + 0.5f*m2n);
                if (eS)  V3  += a * (-1.0f - 0.5f*m2n);
            }
            if (eW) {   // n = i-1,  M[n,i] = E_n
                const int n = i - 1;
                const float m1n = m1b[n*NT+t], m2n = m2b[n*NT+t];
                float wn = 1.0f;
                if (c != 0) { const float ta = tb[n*NT+t]; wn = 1.0f/(ta*ta); }
                const float En = -1.0f + 0.5f*m1n;
                const float a  = wn * En;
                V5 += a * dg;
                V6 += a * En;
                if (eW2) V4 += a * (-1.0f - 0.5f*m1n);
                if (eN)  V9 += a * (-1.0f + 0.5f*m2n);
                if (eS)  V1 += a * (-1.0f - 0.5f*m2n);
            }
            if (eN) {   // n = i+32, M[n,i] = S_n
                const int n = i + 32;
                const float m1n = m1b[n*NT+t], m2n = m2b[n*NT+t];
                float wn = 1.0f;
                if (c != 0) { const float ta = tb[n*NT+t]; wn = 1.0f/(ta*ta); }
                const float Sn = -1.0f - 0.5f*m2n;
                const float a  = wn * Sn;
                V10 += a * dg;
                V6  += a * Sn;
                if (eE)  V11 += a * (-1.0f + 0.5f*m1n);
                if (eW)  V9  += a * (-1.0f - 0.5f*m1n);
                if (eN2) V12 += a * (-1.0f + 0.5f*m2n);
            }
            if (eS) {   // n = i-32, M[n,i] = N_n
                const int n = i - 32;
                const float m1n = m1b[n*NT+t], m2n = m2b[n*NT+t];
                float wn = 1.0f;
                if (c != 0) { const float ta = tb[n*NT+t]; wn = 1.0f/(ta*ta); }
                const float Nn = -1.0f + 0.5f*m2n;
                const float a  = wn * Nn;
                V2 += a * dg;
                V6 += a * Nn;
                if (eE)  V3 += a * (-1.0f + 0.5f*m1n);
                if (eW)  V1 += a * (-1.0f - 0.5f*m1n);
                if (eS2) V0 += a * (-1.0f - 0.5f*m2n);
            }
            if (c == 0) V6 += 1.05f;
            else if (c <= 7) { const float ta = tb[i*NT+t]; V6 += 1.0f/(ta*ta); }
        } else if (c < 17) {               // L: L[i,k] = -w[k]*M[k,i]
            const int t = c - 8;
            { const float ta = tb[i*NT+t];      V6  = -(1.0f/(ta*ta)) * diagM; }
            if (eE) { const float ta = tb[(i+1)*NT+t];
                      V7  = -(1.0f/(ta*ta)) * (-1.0f - 0.5f*m1b[(i+1)*NT+t]); }
            if (eW) { const float ta = tb[(i-1)*NT+t];
                      V5  = -(1.0f/(ta*ta)) * (-1.0f + 0.5f*m1b[(i-1)*NT+t]); }
            if (eN) { const float ta = tb[(i+32)*NT+t];
                      V10 = -(1.0f/(ta*ta)) * (-1.0f - 0.5f*m2b[(i+32)*NT+t]); }
            if (eS) { const float ta = tb[(i-32)*NT+t];
                      V2  = -(1.0f/(ta*ta)) * (-1.0f + 0.5f*m2b[(i-32)*NT+t]); }
        } else {                            // U: U[i,k] = -w[i]*M[i,k]
            const int t = c - 16;
            const float ta = tb[i*NT+t];
            const float wi = 1.0f/(ta*ta);
            V6 = -wi * diagM;
            if (eE) V7  = -wi * (-1.0f + 0.5f*m1b[i*NT+t]);
            if (eW) V5  = -wi * (-1.0f - 0.5f*m1b[i*NT+t]);
            if (eN) V10 = -wi * (-1.0f + 0.5f*m2b[i*NT+t]);
            if (eS) V2  = -wi * (-1.0f - 0.5f*m2b[i*NT+t]);
        }

        tab[c][0]=V0;  tab[c][1]=V1;  tab[c][2]=V2;  tab[c][3]=V3;
        tab[c][4]=V4;  tab[c][5]=V5;  tab[c][6]=V6;  tab[c][7]=V7;
        tab[c][8]=V8;  tab[c][9]=V9;  tab[c][10]=V10; tab[c][11]=V11;
        tab[c][12]=V12; tab[c][13]=0.0f;
    }

    // ---------- overlap: fully-out-of-band threads stream zeros NOW ----------
    // (their bytes don't depend on the table; stores are fire-and-forget and
    //  are NOT drained at the raw barrier below)
    if (alloob) {
        const f32x4 z = (f32x4)(0.0f);
#pragma unroll
        for (int c = 0; c < NCH; ++c)
            *reinterpret_cast<f32x4*>(orow + (size_t)c * NN * NN) = z;
    }

    // raw barrier: make LDS writes visible, but do NOT wait on vmcnt
    asm volatile("s_waitcnt lgkmcnt(0)\n\ts_barrier" ::: "memory");

    // ---------- phase 2: in-band threads stream from the table ----------
    if (!alloob) {
        const char* tb0 = (const char*)&tab[0][0];
        const char* a0 = tb0 + off0;
        const char* a1 = tb0 + off1;
        const char* a2 = tb0 + off2;
        const char* a3 = tb0 + off3;
#pragma unroll
        for (int c = 0; c < NCH; ++c) {
            f32x4 v;
            v[0] = *(const float*)(a0 + c * 56);
            v[1] = *(const float*)(a1 + c * 56);
            v[2] = *(const float*)(a2 + c * 56);
            v[3] = *(const float*)(a3 + c * 56);
            *reinterpret_cast<f32x4*>(orow + (size_t)c * NN * NN) = v;
        }
    }
}

extern "C" void kernel_launch(void* const* d_in, const int* in_sizes, int n_in,
                              void* d_out, int out_size, void* d_ws, size_t ws_size,
                              hipStream_t stream) {
    const float* kappa = (const float*)d_in[0];
    const float* m     = (const float*)d_in[1];
    // d_in[2] = H (unused)
    const float* tau   = (const float*)d_in[3];
    float* out = (float*)d_out;

    spde_kernel<<<BATCH * NN, 256, 0, stream>>>(kappa, m, tau, out);
}